// Round 1
// baseline (1640.795 us; speedup 1.0000x reference)
//
#include <hip/hip_runtime.h>
#include <math.h>

#define DIM 7168
#define NE 256
#define NG 8
#define GSZ 32
#define TOPG 4
#define TOPK_N 8
#define BM 32
#define BK 16
#define NTHR 512

__global__ __launch_bounds__(NTHR, 2) void gate_kernel(
    const float* __restrict__ x, const float* __restrict__ w,
    const float* __restrict__ bias, float* __restrict__ out, int n)
{
    // 64 KB LDS, overlaid: [GEMM staging tiles] then [scores 32x256 double]
    __shared__ double smem[8192];
    double (*w_t)[257]   = reinterpret_cast<double(*)[257]>(smem);            // [BK][257]
    double (*x_t)[BK+1]  = reinterpret_cast<double(*)[BK+1]>(smem + BK*257);  // [BM][17]
    double (*sc)[NE]     = reinterpret_cast<double(*)[NE]>(smem);             // [BM][256] overlay

    const int tid    = threadIdx.x;
    const int row0   = blockIdx.x * BM;
    const int lane_e = tid & 31;        // expert base within 32
    const int tr     = tid >> 5;        // 0..15
    const int r0     = tr * 2;          // rows r0, r0+1 of tile

    double acc[2][8];
#pragma unroll
    for (int i = 0; i < 2; ++i)
#pragma unroll
        for (int j = 0; j < 8; ++j) acc[i][j] = 0.0;

    for (int k0 = 0; k0 < DIM; k0 += BK) {
        __syncthreads();   // protect LDS from previous iteration's readers
        // stage W chunk: 256 experts x BK floats -> double, transposed [k][e]
        {
            int e  = tid >> 2;
            int i4 = (tid & 3) * 4;
#pragma unroll
            for (int p = 0; p < 2; ++p, e += 128) {
                const float4 v = *reinterpret_cast<const float4*>(
                    &w[(size_t)e * DIM + k0 + i4]);
                w_t[i4 + 0][e] = (double)v.x;
                w_t[i4 + 1][e] = (double)v.y;
                w_t[i4 + 2][e] = (double)v.z;
                w_t[i4 + 3][e] = (double)v.w;
            }
            // stage x chunk: 32 rows x BK floats
            int r  = tid >> 4;
            int kk = tid & 15;
            int grow = row0 + r;
            x_t[r][kk] = (grow < n) ? (double)x[(size_t)grow * DIM + k0 + kk] : 0.0;
        }
        __syncthreads();
#pragma unroll
        for (int kk = 0; kk < BK; ++kk) {
            double x0 = x_t[r0][kk];
            double x1 = x_t[r0 + 1][kk];
#pragma unroll
            for (int j = 0; j < 8; ++j) {
                double wv = w_t[kk][lane_e + 32 * j];
                acc[0][j] = fma(x0, wv, acc[0][j]);
                acc[1][j] = fma(x1, wv, acc[1][j]);
            }
        }
    }
    __syncthreads();
    // dump scores to LDS (overlay region)
#pragma unroll
    for (int i = 0; i < 2; ++i)
#pragma unroll
        for (int j = 0; j < 8; ++j)
            sc[r0 + i][lane_e + 32 * j] = acc[i][j];
    __syncthreads();

    // routing: one thread per row (threads 0..31)
    if (tid < BM) {
        const int row = row0 + tid;
        if (row < n) {
            // softmax (double)
            double zmax = -1e300;
            for (int e = 0; e < NE; ++e) zmax = fmax(zmax, sc[tid][e]);
            double Z = 0.0;
            for (int e = 0; e < NE; ++e) {
                double p = exp(sc[tid][e] - zmax);
                sc[tid][e] = p;           // row-private: safe in-place
                Z += p;
            }
            const double invZ = 1.0 / Z;

            // group scores: sum of top-2 of (p*invZ + bias) per group of 32
            double gs[NG];
            for (int g = 0; g < NG; ++g) {
                double m1 = -1e300, m2 = -1e300;
                for (int i = 0; i < GSZ; ++i) {
                    double v = sc[tid][g * GSZ + i] * invZ + (double)bias[g * GSZ + i];
                    if (v > m1) { m2 = m1; m1 = v; }
                    else if (v > m2) { m2 = v; }
                }
                gs[g] = m1 + m2;
            }
            // top-4 groups (strict > keeps lowest index on ties, like lax.top_k)
            unsigned keep = 0;
            for (int t = 0; t < TOPG; ++t) {
                double best = -1e300; int bg = 0;
                for (int g = 0; g < NG; ++g)
                    if (!((keep >> g) & 1u) && gs[g] > best) { best = gs[g]; bg = g; }
                keep |= 1u << bg;
            }
            // top-8 experts among kept groups
            unsigned long long tk[4] = {0ull, 0ull, 0ull, 0ull};
            float* out_w = out;
            float* out_i = out + (size_t)n * TOPK_N;
            for (int t = 0; t < TOPK_N; ++t) {
                double best = -1e300; int be = 0;
                for (int e = 0; e < NE; ++e) {
                    if (!((keep >> (e >> 5)) & 1u)) continue;
                    if ((tk[e >> 6] >> (e & 63)) & 1ull) continue;
                    double s = sc[tid][e] * invZ + (double)bias[e];
                    if (s > best) { best = s; be = e; }
                }
                tk[be >> 6] |= 1ull << (be & 63);
                out_w[(size_t)row * TOPK_N + t] = (float)(sc[tid][be] * invZ * 2.5);
                out_i[(size_t)row * TOPK_N + t] = (float)be;
            }
        }
    }
}

extern "C" void kernel_launch(void* const* d_in, const int* in_sizes, int n_in,
                              void* d_out, int out_size, void* d_ws, size_t ws_size,
                              hipStream_t stream) {
    const float* x  = (const float*)d_in[0];
    const float* w  = (const float*)d_in[1];
    const float* b  = (const float*)d_in[2];
    float* out      = (float*)d_out;
    const int n     = in_sizes[0] / DIM;
    const int nblk  = (n + BM - 1) / BM;
    gate_kernel<<<nblk, NTHR, 0, stream>>>(x, w, b, out, n);
}

// Round 3
// 1023.471 us; speedup vs baseline: 1.6032x; 1.6032x over previous
//
#include <hip/hip_runtime.h>
#include <math.h>

#define DIM 7168
#define NE 256
#define NG 8
#define GSZ 32
#define TOPG 4
#define TOPK_N 8
#define BM 32
#define BK 16
#define NTHR 512
#define NCHUNK (DIM / BK)   // 448

__global__ __launch_bounds__(NTHR, 4) void gate_kernel(
    const float* __restrict__ x, const float* __restrict__ w,
    const float* __restrict__ bias, float* __restrict__ out, int n)
{
    // 64 KB LDS: staging w_t[16][256] + x_t[16][32], overlaid later by sc[32][256]
    __shared__ __align__(16) double smem[8192];
    double (*w_t)[NE] = reinterpret_cast<double(*)[NE]>(smem);            // [16][256] w^T
    double (*x_t)[BM] = reinterpret_cast<double(*)[BM]>(smem + BK * NE);  // [16][32]  x^T
    double (*sc)[NE]  = reinterpret_cast<double(*)[NE]>(smem);            // overlay [32][256]

    const int t    = threadIdx.x;
    const int row0 = blockIdx.x * BM;

    // ---- staging assignment (identical pattern to round 1/2) ----
    const int ep = t & 127;           // experts 2ep, 2ep+1
    const int h  = t >> 7;            // k quad 4h..4h+3
    const long wrowA = (long)(2 * ep) * DIM + 4 * h;
    const long wrowB = (long)(2 * ep + 1) * DIM + 4 * h;
    const int sxr = t >> 3;           // t<256: row 0..31
    const int sxk = (t & 7) * 2;      // k pair
    long xoff = 0;
    if (t < 256) {
        int rr = row0 + sxr; if (rr > n - 1) rr = n - 1;
        xoff = (long)rr * DIM + sxk;
    }

    // ---- compute assignment: 4 rows x 4 experts per thread ----
    const int wid   = t >> 6;         // 0..7 -> expert block 32*wid
    const int lane  = t & 63;
    const int lr    = lane >> 3;      // 0..7 -> rows 4lr..4lr+3
    const int le    = lane & 7;       // 0..7 -> experts 32wid+4le..+3
    const int rbase = 4 * lr;
    const int ebase = 32 * wid + 4 * le;

    double acc[4][4];
#pragma unroll
    for (int i = 0; i < 4; ++i)
#pragma unroll
        for (int j = 0; j < 4; ++j) acc[i][j] = 0.0;

    // prefetch chunk 0
    float4 pwa = *(const float4*)&w[wrowA];
    float4 pwb = *(const float4*)&w[wrowB];
    float2 pxv = {0.f, 0.f};
    if (t < 256) pxv = *(const float2*)&x[xoff];

    for (int c = 0; c < NCHUNK; ++c) {
        __syncthreads();   // previous chunk fully consumed
        // staged regs -> LDS (f32 -> f64)
        {
            const float* fa = reinterpret_cast<const float*>(&pwa);
            const float* fb = reinterpret_cast<const float*>(&pwb);
#pragma unroll
            for (int q = 0; q < 4; ++q) {
                double2 v; v.x = (double)fa[q]; v.y = (double)fb[q];
                *reinterpret_cast<double2*>(&w_t[4 * h + q][2 * ep]) = v;
            }
            if (t < 256) {
                x_t[sxk    ][sxr] = (double)pxv.x;
                x_t[sxk + 1][sxr] = (double)pxv.y;
            }
        }
        // issue next chunk's global loads (in flight under compute)
        {
            const int  cn = (c + 1 < NCHUNK) ? (c + 1) : c;
            const long k0 = (long)cn * BK;
            pwa = *(const float4*)&w[wrowA + k0];
            pwb = *(const float4*)&w[wrowB + k0];
            if (t < 256) pxv = *(const float2*)&x[xoff + k0];
        }
        __syncthreads();   // LDS visible
#pragma unroll
        for (int kk = 0; kk < BK; ++kk) {
            double2 xa = *reinterpret_cast<const double2*>(&x_t[kk][rbase]);
            double2 xb = *reinterpret_cast<const double2*>(&x_t[kk][rbase + 2]);
            double2 wa = *reinterpret_cast<const double2*>(&w_t[kk][ebase]);
            double2 wb = *reinterpret_cast<const double2*>(&w_t[kk][ebase + 2]);
            const double xr[4] = {xa.x, xa.y, xb.x, xb.y};
            const double wv[4] = {wa.x, wa.y, wb.x, wb.y};
#pragma unroll
            for (int i = 0; i < 4; ++i)
#pragma unroll
                for (int j = 0; j < 4; ++j)
                    acc[i][j] = fma(xr[i], wv[j], acc[i][j]);
        }
    }

    __syncthreads();   // done with w_t/x_t; safe to overlay sc
#pragma unroll
    for (int i = 0; i < 4; ++i) {
        double2 v0; v0.x = acc[i][0]; v0.y = acc[i][1];
        double2 v1; v1.x = acc[i][2]; v1.y = acc[i][3];
        *reinterpret_cast<double2*>(&sc[rbase + i][ebase])     = v0;
        *reinterpret_cast<double2*>(&sc[rbase + i][ebase + 2]) = v1;
    }
    __syncthreads();

    // ---- routing: round-1 verbatim (serial per row, threads 0..31) ----
    if (t < BM) {
        const int row = row0 + t;
        if (row < n) {
            double zmax = -1e300;
            for (int e = 0; e < NE; ++e) zmax = fmax(zmax, sc[t][e]);
            double Z = 0.0;
            for (int e = 0; e < NE; ++e) {
                double p = exp(sc[t][e] - zmax);
                sc[t][e] = p;           // row-private: safe in-place
                Z += p;
            }
            const double invZ = 1.0 / Z;

            double gs[NG];
            for (int g = 0; g < NG; ++g) {
                double m1 = -1e300, m2 = -1e300;
                for (int i = 0; i < GSZ; ++i) {
                    double v = sc[t][g * GSZ + i] * invZ + (double)bias[g * GSZ + i];
                    if (v > m1) { m2 = m1; m1 = v; }
                    else if (v > m2) { m2 = v; }
                }
                gs[g] = m1 + m2;
            }
            unsigned keep = 0;
            for (int tt = 0; tt < TOPG; ++tt) {
                double best = -1e300; int bg = 0;
                for (int g = 0; g < NG; ++g)
                    if (!((keep >> g) & 1u) && gs[g] > best) { best = gs[g]; bg = g; }
                keep |= 1u << bg;
            }
            unsigned long long tk[4] = {0ull, 0ull, 0ull, 0ull};
            float* out_w = out;
            float* out_i = out + (size_t)n * TOPK_N;
            for (int pp = 0; pp < TOPK_N; ++pp) {
                double best = -1e300; int be = 0;
                for (int e = 0; e < NE; ++e) {
                    if (!((keep >> (e >> 5)) & 1u)) continue;
                    if ((tk[e >> 6] >> (e & 63)) & 1ull) continue;
                    double s = sc[t][e] * invZ + (double)bias[e];
                    if (s > best) { best = s; be = e; }
                }
                tk[be >> 6] |= 1ull << (be & 63);
                out_w[(size_t)row * TOPK_N + pp] = (float)(sc[t][be] * invZ * 2.5);
                out_i[(size_t)row * TOPK_N + pp] = (float)be;
            }
        }
    }
}

extern "C" void kernel_launch(void* const* d_in, const int* in_sizes, int n_in,
                              void* d_out, int out_size, void* d_ws, size_t ws_size,
                              hipStream_t stream) {
    const float* x  = (const float*)d_in[0];
    const float* w  = (const float*)d_in[1];
    const float* b  = (const float*)d_in[2];
    float* out      = (float*)d_out;
    const int n     = in_sizes[0] / DIM;
    const int nblk  = (n + BM - 1) / BM;
    gate_kernel<<<nblk, NTHR, 0, stream>>>(x, w, b, out, n);
}